// Round 13
// baseline (304.312 us; speedup 1.0000x reference)
//
#include <hip/hip_runtime.h>
#include <stdint.h>

#define GN 50000
#define GE 800000
#define CSTRIDE 64  // padded CSR row stride (max in-degree ~45 for Poisson(16))
#define DSTRIDE 32  // atomic-counter padding: 128 B per counter (write path only)
#define ROWS 64     // rows per block
#define BLK 256     // threads per block (4 waves); 4 threads per node in gather

typedef unsigned int uint;
typedef unsigned short ushort_t;

// bf16 round-to-nearest-even, f32 -> bits
__device__ inline uint f2b(float f) {
  uint u = __float_as_uint(f);
  return (u + 0x7fffu + ((u >> 16) & 1u)) >> 16;
}
// accumulate 2 bf16 (packed in u) * sc into a[o], a[o+1]
__device__ inline void bacc(float* a, uint u, float sc, int o) {
  a[o]     += __uint_as_float(u << 16) * sc;
  a[o + 1] += __uint_as_float(u & 0xffff0000u) * sc;
}

// ---- fused: deg_out histogram + padded-CSR fill by dst (padded counters: atomic path) ----
__global__ __launch_bounds__(256) void fill_count_kernel(
    const int* __restrict__ src, const int* __restrict__ dst,
    uint* __restrict__ deg_out, uint* __restrict__ cursor,
    ushort_t* __restrict__ csrp) {
  int e = blockIdx.x * 256 + threadIdx.x;
  if (e >= GE) return;
  int s = src[e], d = dst[e];
  uint pos = atomicAdd(&cursor[d * DSTRIDE], 1u);
  if (pos < CSTRIDE) csrp[d * CSTRIDE + pos] = (ushort_t)s;  // safety guard
  atomicAdd(&deg_out[s * DSTRIDE], 1u);
}

// ---- compact read-side arrays from padded counters (R9: reads need 200KB, not 6.4MB) ----
__global__ __launch_bounds__(256) void norm_kernel(
    const uint* __restrict__ cursor_p, const uint* __restrict__ dego_p,
    uint* __restrict__ din, float* __restrict__ ns, float* __restrict__ nd) {
  int i = blockIdx.x * 256 + threadIdx.x;
  if (i >= GN) return;
  uint di_ = cursor_p[i * DSTRIDE];
  uint do_ = dego_p[i * DSTRIDE];
  din[i] = di_;
  nd[i] = rsqrtf(fmaxf((float)di_, 1.f));
  ns[i] = rsqrtf(fmaxf((float)do_, 1.f));
}

// ---- x (f32) -> bf16 packed; one float4 -> one uint2 ----
__global__ __launch_bounds__(256) void convx_kernel(
    const float4* __restrict__ X4, uint2* __restrict__ xb) {
  int idx = blockIdx.x * 256 + threadIdx.x;
  if (idx >= GN * 24) return;
  float4 v = X4[idx];
  uint2 o;
  o.x = f2b(v.x) | (f2b(v.y) << 16);
  o.y = f2b(v.z) | (f2b(v.w) << 16);
  xb[idx] = o;
}

// ---- fused gather(bf16 H, 4 thr/node, uint4 loads) + GEMM 96x96 (f32) + epilogue ----
// gather: agg[n] = sum_{nb in csr row n} (LAYER==1 ? ns[nb] : 1) * H[nb]
// LAYER==1: h1b[r][c] = bf16( relu(nd[r]*acc + b[c]) * ns[r] )
// LAYER==2: colmax over relu(nd[r]*acc + b[c]) -> atomicMax gmax
template <int LAYER>
__global__ __launch_bounds__(BLK) void fgemm_kernel(
    const uint* __restrict__ Hb, const ushort_t* __restrict__ csrp,
    const uint* __restrict__ din, const float* __restrict__ ns,
    const float* __restrict__ nd, const float* __restrict__ W,
    const float* __restrict__ bias, ushort_t* __restrict__ outHb,
    int* __restrict__ gmax) {
  __shared__ float4 Wt[12][96];     // half of W: 48 k-rows -> 18,432 B
  __shared__ float4 Asm[ROWS][24];  // gathered agg tile    -> 24,576 B
  __shared__ float red[4][96];      //                      ->  1,536 B (tot 44,544)
  const int tid = threadIdx.x;
  const int row0 = blockIdx.x * ROWS;

  // stage W half 0 (k rows 0..47); latency hides under gather
  for (int idx = tid; idx < 48 * 96; idx += BLK) {
    int k = idx / 96, cc = idx - k * 96;
    ((float*)&Wt[k >> 2][cc])[k & 3] = W[k * 96 + cc];
  }

  // gather: 4 threads per node; thread sub owns 24 consecutive k-cols.
  // bf16 row = 12 uint4; thread reads uint4s [3*sub, 3*sub+3) -> 12 lane-requests
  // per edge total (R11 had 24: the invariant that never moved — halve it).
  {
    const int r = tid >> 2, sub = tid & 3;
    const int n = row0 + r;
    float a[24];
    #pragma unroll
    for (int j = 0; j < 24; ++j) a[j] = 0.f;
    if (n < GN) {
      uint d = din[n]; if (d > CSTRIDE) d = CSTRIDE;  // never triggers; safety
      const ushort_t* crow = csrp + n * CSTRIDE;
      for (uint i = 0; i < d; ++i) {
        int nb = (int)crow[i];
        const uint4* hp = (const uint4*)(Hb + nb * 48) + 3 * sub;
        uint4 q0 = hp[0], q1 = hp[1], q2 = hp[2];
        float sc = 1.f;
        if (LAYER == 1) sc = ns[nb];
        bacc(a, q0.x, sc, 0);  bacc(a, q0.y, sc, 2);
        bacc(a, q0.z, sc, 4);  bacc(a, q0.w, sc, 6);
        bacc(a, q1.x, sc, 8);  bacc(a, q1.y, sc, 10);
        bacc(a, q1.z, sc, 12); bacc(a, q1.w, sc, 14);
        bacc(a, q2.x, sc, 16); bacc(a, q2.y, sc, 18);
        bacc(a, q2.z, sc, 20); bacc(a, q2.w, sc, 22);
      }
    }
    #pragma unroll
    for (int j4 = 0; j4 < 6; ++j4)
      Asm[r][6 * sub + j4] =
          make_float4(a[4 * j4], a[4 * j4 + 1], a[4 * j4 + 2], a[4 * j4 + 3]);
  }
  __syncthreads();   // Asm + Wt(half0) ready

  // GEMM phase: 4 waves x 16 rows; K split in two halves of 48
  const int w = tid >> 6, lane = tid & 63, rh = lane >> 5, c = lane & 31;
  const int rbase = w * 16 + rh * 8;

  float acc[8][3];
  #pragma unroll
  for (int j = 0; j < 8; ++j)
    #pragma unroll
    for (int m = 0; m < 3; ++m) acc[j][m] = 0.f;

  #pragma unroll 2
  for (int kc = 0; kc < 12; ++kc) {
    float4 w0 = Wt[kc][c];
    float4 w1 = Wt[kc][c + 32];
    float4 w2 = Wt[kc][c + 64];
    #pragma unroll
    for (int j = 0; j < 8; ++j) {
      float4 a = Asm[rbase + j][kc];
      acc[j][0] += a.x * w0.x + a.y * w0.y + a.z * w0.z + a.w * w0.w;
      acc[j][1] += a.x * w1.x + a.y * w1.y + a.z * w1.z + a.w * w1.w;
      acc[j][2] += a.x * w2.x + a.y * w2.y + a.z * w2.z + a.w * w2.w;
    }
  }
  __syncthreads();   // done reading Wt half0

  // stage W half 1 (k rows 48..95)
  for (int idx = tid; idx < 48 * 96; idx += BLK) {
    int k = idx / 96, cc = idx - k * 96;
    ((float*)&Wt[k >> 2][cc])[k & 3] = W[(48 + k) * 96 + cc];
  }
  __syncthreads();   // Wt half1 ready

  #pragma unroll 2
  for (int kc = 0; kc < 12; ++kc) {
    float4 w0 = Wt[kc][c];
    float4 w1 = Wt[kc][c + 32];
    float4 w2 = Wt[kc][c + 64];
    #pragma unroll
    for (int j = 0; j < 8; ++j) {
      float4 a = Asm[rbase + j][kc + 12];
      acc[j][0] += a.x * w0.x + a.y * w0.y + a.z * w0.z + a.w * w0.w;
      acc[j][1] += a.x * w1.x + a.y * w1.y + a.z * w1.z + a.w * w1.w;
      acc[j][2] += a.x * w2.x + a.y * w2.y + a.z * w2.z + a.w * w2.w;
    }
  }

  float colmax[3] = {0.f, 0.f, 0.f};
  #pragma unroll
  for (int j = 0; j < 8; ++j) {
    int row = row0 + rbase + j;
    if (row < GN) {
      float ndv = nd[row];
      float nsv = (LAYER == 1) ? ns[row] : 0.f;
      #pragma unroll
      for (int m = 0; m < 3; ++m) {
        float v = ndv * acc[j][m] + bias[c + 32 * m];
        v = fmaxf(v, 0.f);
        if (LAYER == 1) outHb[row * 96 + c + 32 * m] = (ushort_t)f2b(v * nsv);
        else            colmax[m] = fmaxf(colmax[m], v);
      }
    }
  }

  if (LAYER == 2) {
    #pragma unroll
    for (int m = 0; m < 3; ++m)
      colmax[m] = fmaxf(colmax[m], __shfl_xor(colmax[m], 32, 64));
    if (rh == 0) {
      red[w][c]      = colmax[0];
      red[w][c + 32] = colmax[1];
      red[w][c + 64] = colmax[2];
    }
    __syncthreads();
    if (tid < 96) {
      float v = fmaxf(fmaxf(red[0][tid], red[1][tid]),
                      fmaxf(red[2][tid], red[3][tid]));
      atomicMax(gmax + tid, __float_as_int(v));  // all vals >= 0 (relu)
    }
  }
}

// ---- final tiny GEMV: out = gmax @ Wl + bl ----
__global__ __launch_bounds__(64) void final_kernel(
    const float* __restrict__ gmaxf, const float* __restrict__ Wl,
    const float* __restrict__ bl, float* __restrict__ out) {
  int l = threadIdx.x;
  float g1 = gmaxf[l];
  float p0 = g1 * Wl[l * 2 + 0];
  float p1 = g1 * Wl[l * 2 + 1];
  if (l < 32) {
    float g2 = gmaxf[64 + l];
    p0 += g2 * Wl[(64 + l) * 2 + 0];
    p1 += g2 * Wl[(64 + l) * 2 + 1];
  }
  #pragma unroll
  for (int off = 32; off; off >>= 1) {
    p0 += __shfl_down(p0, off, 64);
    p1 += __shfl_down(p1, off, 64);
  }
  if (l == 0) { out[0] = p0 + bl[0]; out[1] = p1 + bl[1]; }
}

extern "C" void kernel_launch(void* const* d_in, const int* in_sizes, int n_in,
                              void* d_out, int out_size, void* d_ws, size_t ws_size,
                              hipStream_t stream) {
  const float* x   = (const float*)d_in[0];
  const int*   src = (const int*)d_in[1];
  const int*   dst = (const int*)d_in[2];
  const float* W1  = (const float*)d_in[3];
  const float* b1  = (const float*)d_in[4];
  const float* W2  = (const float*)d_in[5];
  const float* b2  = (const float*)d_in[6];
  const float* Wl  = (const float*)d_in[7];
  const float* bl  = (const float*)d_in[8];
  float* out = (float*)d_out;

  // workspace layout (bytes)
  char* ws = (char*)d_ws;
  uint*     cursor  = (uint*)(ws + 0);           // 6,400,000 (padded; ends == deg_in)
  uint*     deg_out = (uint*)(ws + 6400000);     // 6,400,000 (padded)
  int*      gmax    = (int*)(ws + 12800000);     // 384 (padded to 4096)
  uint*     din     = (uint*)(ws + 12804096);    // 200,000 compact
  float*    ns      = (float*)(ws + 13004096);   // 200,000 compact
  float*    nd      = (float*)(ws + 13204096);   // 200,000 compact
  ushort_t* csrp    = (ushort_t*)(ws + 13404096);// 6,400,000
  uint*     xb      = (uint*)(ws + 19804096);    // 9,600,000 (x in bf16, 16B-aligned)
  ushort_t* h1b     = (ushort_t*)(ws + 29404096);// 9,600,000 (h1 in bf16, 16B-aligned)

  // zero: cursor, deg_out, gmax (contiguous prefix)
  hipMemsetAsync(d_ws, 0, 12800384, stream);

  fill_count_kernel<<<(GE + 255) / 256, 256, 0, stream>>>(
      src, dst, deg_out, cursor, csrp);
  norm_kernel<<<(GN + 255) / 256, 256, 0, stream>>>(
      cursor, deg_out, din, ns, nd);
  convx_kernel<<<(GN * 24 + 255) / 256, 256, 0, stream>>>(
      (const float4*)x, (uint2*)xb);
  // layer 1: gather(bf16 x * ns[src]) + GEMM + relu (+ns pre-scale) -> h1b (bf16)
  fgemm_kernel<1><<<(GN + ROWS - 1) / ROWS, BLK, 0, stream>>>(
      xb, csrp, din, ns, nd, W1, b1, h1b, nullptr);
  // layer 2: gather(bf16 h1) + GEMM + relu + colmax -> gmax
  fgemm_kernel<2><<<(GN + ROWS - 1) / ROWS, BLK, 0, stream>>>(
      (const uint*)h1b, csrp, din, ns, nd, W2, b2, nullptr, gmax);
  final_kernel<<<1, 64, 0, stream>>>((const float*)gmax, Wl, bl, out);
}